// Round 12
// baseline (275.422 us; speedup 1.0000x reference)
//
#include <hip/hip_runtime.h>
#include <stdint.h>

// ---------------- types ----------------
typedef _Float16 f16x8 __attribute__((ext_vector_type(8)));
typedef __fp16   fp16x2 __attribute__((ext_vector_type(2)));
typedef float    f32x16 __attribute__((ext_vector_type(16)));

union Frag {
  f16x8    v;
  uint32_t w[4];
  _Float16 h[8];
};

union CVec {
  float4 q[4];
  f32x16 v;
};

__device__ __forceinline__ uint32_t pack2h(float a, float b) {
  union { _Float16 h[2]; uint32_t u; } r;
  r.h[0] = (_Float16)a;   // RNE f32->f16
  r.h[1] = (_Float16)b;
  return r.u;
}

__device__ __forceinline__ uint32_t pkrtz(float a, float b) {
  union { fp16x2 h2; uint32_t u; } cv;
  cv.h2 = __builtin_amdgcn_cvt_pkrtz(a, b);
  return cv.u;
}

__device__ __forceinline__ void g2lds16(const void* g, void* l) {
  __builtin_amdgcn_global_load_lds(
      (const __attribute__((address_space(1))) uint32_t*)g,
      (__attribute__((address_space(3))) uint32_t*)l, 16, 0, 0);
}

// Channel relabeling (involution) applied to W rows + bias of EVERY layer:
// slot s (0..31 within a 32-tile) holds logical channel lam32(s).
// With this, D-reg pairs are already in B-fragment k-order -> NO lane exchange.
__host__ __device__ __forceinline__ int lam32(int s) {
  return (((s >> 2) ^ (s >> 3)) & 1) ? (s ^ 12) : s;
}

// ---------------- prep: fragment-order the weights (f16) ----------------
// ws layout (bytes):
//   wfrag   @ 0      : [9][8 kt][4 ot][64 lane][8 j] f16  = 294912 B  (streaming order!)
//   w0frag  @ 294912 : [4 ot][64 lane][8 j]          f16  = 4096 B   (K padded 4->16)
//   biasC   @ 299008 : [10 l][4 ot][2 h][16 r]       f32  = 5120 B   (MFMA C-operand order)
//   woutf16 @ 304128 : [8 kt][64 lane][8 j]          f16  = 8192 B   (A-frag, rows!=0 zeroed)
// fragment value convention (32x32x16 f16 MFMA):
//   A lane l holds row i = l&31, k = (l>>5)*8 + j
//   B lane l holds col j = l&31, k = (l>>5)*8 + j
//   D/C lane l holds col = l&31, row r: slot = (r&3) + 8*(r>>2) + 4*(l>>5)
// W is read straight from global (L2-resident, L1 dedups the 8-wave reuse);
// [kt][ot] ordering matches the access order -> pure 32KB linear stream/layer.
__global__ void prep_kernel(const float* __restrict__ W0, const float* __restrict__ b0,
                            const float* __restrict__ Wh, const float* __restrict__ bh,
                            const float* __restrict__ Wout,
                            _Float16* __restrict__ wfrag, _Float16* __restrict__ w0frag,
                            float* __restrict__ biasC, _Float16* __restrict__ woutf16) {
  const int stride = gridDim.x * blockDim.x;
  for (int idx = blockIdx.x * blockDim.x + threadIdx.x; idx < 154880; idx += stride) {
    if (idx < 147456) {                       // wfrag: Wh[l][lam(o)][k], [l][kt][ot] order
      const int j = idx & 7, lane = (idx >> 3) & 63, ot = (idx >> 9) & 3,
                kt = (idx >> 11) & 7, l = idx >> 14;
      const int o = ot * 32 + lam32(lane & 31);
      const int k = kt * 16 + (lane >> 5) * 8 + j;
      wfrag[idx] = (_Float16)Wh[(l * 128 + o) * 128 + k];
    } else if (idx < 147456 + 2048) {         // w0frag (K padded with zeros), rows lam'd
      const int i = idx - 147456;
      const int j = i & 7, lane = (i >> 3) & 63, ot = i >> 9;
      const int o = ot * 32 + lam32(lane & 31);
      const int k = (lane >> 5) * 8 + j;
      w0frag[i] = (_Float16)(k < 4 ? W0[o * 4 + k] : 0.0f);
    } else if (idx < 147456 + 2048 + 1280) {  // biasC: C-operand order per (l,ot,h), lam'd
      const int i = idx - (147456 + 2048);
      const int r = i & 15, hh = (i >> 4) & 1, ot = (i >> 5) & 3, l = i >> 7;
      const int slot = (r & 3) + 8 * (r >> 2) + 4 * hh;
      const int o = ot * 32 + lam32(slot);
      biasC[i] = (l == 0) ? b0[o] : bh[(l - 1) * 128 + o];
    } else {                                  // Wout as masked A-fragment (row 0 only), f16
      const int i = idx - (147456 + 2048 + 1280);
      const int j = i & 7, lane = (i >> 3) & 63, kt = i >> 9;
      const int k = kt * 16 + (lane >> 5) * 8 + j;   // logical k — unchanged
      woutf16[i] = ((lane & 31) == 0) ? (_Float16)Wout[k] : (_Float16)0.0f;
    }
  }
}

// ---------------- fused MLP: 256 threads, 4 waves x 64 rows (nt=2) ----------------
// W streams from global/L1 per wave — NO LDS W buffer, NO barriers in the main
// loop. Waves run free and drift into anti-phase, covering each other's
// epilogue/load phases on the matrix pipe (register cap = 2 waves/SIMD).
__global__ __launch_bounds__(256, 2) void mlp_fused(
    const float* __restrict__ x,
    const _Float16* __restrict__ wfrag,
    const _Float16* __restrict__ w0frag,
    const float* __restrict__ biasCg,
    const _Float16* __restrict__ woutf16,
    const float* __restrict__ boutp,
    float* __restrict__ out) {
  __shared__ __align__(16) float ldsBiasC[1280];   // bias C-table only (5 KB)

  const int t    = threadIdx.x;
  const int lane = t & 63;
  const int wv   = t >> 6;
  const int h    = lane >> 5;   // half-wave
  const int ln   = lane & 31;
  const long rowbase = (long)blockIdx.x * 256 + wv * 64;  // + nt*32 + ln

  // ---- stage bias C-table once ----
  {
    const unsigned char* bsrc = (const unsigned char*)biasCg;
    g2lds16(bsrc + t * 16, (unsigned char*)ldsBiasC + t * 16);            // 0..4095
    if (t < 64) g2lds16(bsrc + (256 + t) * 16, (unsigned char*)ldsBiasC + (256 + t) * 16);
  }

  Frag   B[2][8];      // current-layer input fragments (H^T), per nt / k-tile
  f32x16 acc[4][2];    // [o-tile][n-tile], D = H_out^T
  const f32x16 fzero = (f32x16)0.0f;

  // broadcast read of the per-(layer,ot,half) C-operand (bias pre-placed in D order)
  auto load_cvec = [&](int l, int ot) -> f32x16 {
    CVec cv;
    const float* p = ldsBiasC + ((l * 4 + ot) * 2 + h) * 16;
#pragma unroll
    for (int g = 0; g < 4; ++g) cv.q[g] = *(const float4*)(p + g * 4);
    return cv.v;
  };

  // x loads + pack overlap the bias staging latency
  Frag xb[2];
#pragma unroll
  for (int nt = 0; nt < 2; ++nt) {
    float4 xv = make_float4(0.f, 0.f, 0.f, 0.f);
    if (h == 0) xv = *(const float4*)(x + (rowbase + nt * 32 + ln) * 4);
    xb[nt].w[0] = pack2h(xv.x, xv.y);
    xb[nt].w[1] = pack2h(xv.z, xv.w);
    xb[nt].w[2] = 0u;
    xb[nt].w[3] = 0u;
  }

  __syncthreads();  // bias table ready — the ONLY barrier

  // ---- layer 0: K=16 zero-padded MFMA, C = bias ----
#pragma unroll
  for (int ot = 0; ot < 4; ++ot) {
    const f16x8 a0 = *(const f16x8*)(w0frag + ot * 512 + lane * 8);
    const f32x16 cvec = load_cvec(0, ot);
    acc[ot][0] = __builtin_amdgcn_mfma_f32_32x32x16_f16(a0, xb[0].v, cvec, 0, 0, 0);
    acc[ot][1] = __builtin_amdgcn_mfma_f32_32x32x16_f16(a0, xb[1].v, cvec, 0, 0, 0);
  }

  // epilogue: relu+pack straight from acc pairs (lam32 pre-permutation makes the
  // D-reg order equal the B-fragment k-order — no lane exchange, no moves).
  auto do_epilogue = [&]() {
#pragma unroll
    for (int ot = 0; ot < 4; ++ot) {
#pragma unroll
      for (int nt = 0; nt < 2; ++nt) {
#pragma unroll
        for (int u = 0; u < 2; ++u) {      // B k-tile half: acc regs 8u..8u+7
          Frag nb;
#pragma unroll
          for (int j = 0; j < 4; ++j) {
            const uint32_t cv = pkrtz(acc[ot][nt][8 * u + 2 * j],
                                      acc[ot][nt][8 * u + 2 * j + 1]);
            uint32_t r;
            asm("v_pk_max_f16 %0, %1, %2" : "=v"(r) : "v"(cv), "v"(0u));
            nb.w[j] = r;
          }
          B[nt][ot * 2 + u] = nb;
        }
      }
    }
  };

  // ---- 9 hidden layers: barrier-free, W streamed from global through L1 ----
  // Rotating A-fragment pipeline: a[ot] refilled with the (kt+1) fragment right
  // after its two MFMAs consume it (~6 MFMA ≈ 200 cyc of latency cover).
#pragma unroll
  for (int l = 1; l <= 9; ++l) {
    const _Float16* wl = wfrag + (size_t)(l - 1) * 16384;  // [kt][ot][lane][j]

    f16x8 a[4];
#pragma unroll
    for (int ot = 0; ot < 4; ++ot)   // preload kt=0 fragments (latency under epilogue)
      a[ot] = *(const f16x8*)(wl + ot * 512 + lane * 8);

    do_epilogue();  // acc(l-1) -> B (register-only)

    __builtin_amdgcn_s_setprio(1);
#pragma unroll
    for (int kt = 0; kt < 8; ++kt) {
#pragma unroll
      for (int ot = 0; ot < 4; ++ot) {
        if (kt == 0) {
          const f32x16 cvec = load_cvec(l, ot);
          acc[ot][0] = __builtin_amdgcn_mfma_f32_32x32x16_f16(a[ot], B[0][kt].v, cvec, 0, 0, 0);
          acc[ot][1] = __builtin_amdgcn_mfma_f32_32x32x16_f16(a[ot], B[1][kt].v, cvec, 0, 0, 0);
        } else {
          acc[ot][0] = __builtin_amdgcn_mfma_f32_32x32x16_f16(a[ot], B[0][kt].v, acc[ot][0], 0, 0, 0);
          acc[ot][1] = __builtin_amdgcn_mfma_f32_32x32x16_f16(a[ot], B[1][kt].v, acc[ot][1], 0, 0, 0);
        }
        if (kt < 7)   // refill the just-freed fragment register with kt+1's data
          a[ot] = *(const f16x8*)(wl + ((kt + 1) * 4 + ot) * 512 + lane * 8);
      }
    }
    __builtin_amdgcn_s_setprio(0);
  }

  // ---- output layer: MFMA with masked Wout A-fragment (row 0 only) ----
  // D row 0 lives in reg 0 of lanes 0..31 -> no shuffle reduce needed.
  {
    Frag wa[8];
#pragma unroll
    for (int kt = 0; kt < 8; ++kt)
      wa[kt].v = *(const f16x8*)(woutf16 + kt * 512 + lane * 8);
    const float boutv = *boutp;

    do_epilogue();  // layer 9 acc -> B

    f32x16 accO0 = fzero, accO1 = fzero;
#pragma unroll
    for (int kt = 0; kt < 8; ++kt) {
      accO0 = __builtin_amdgcn_mfma_f32_32x32x16_f16(wa[kt].v, B[0][kt].v, accO0, 0, 0, 0);
      accO1 = __builtin_amdgcn_mfma_f32_32x32x16_f16(wa[kt].v, B[1][kt].v, accO1, 0, 0, 0);
    }
    if (h == 0) {
      out[rowbase + ln]      = accO0[0] + boutv;
      out[rowbase + 32 + ln] = accO1[0] + boutv;
    }
  }
}

extern "C" void kernel_launch(void* const* d_in, const int* in_sizes, int n_in,
                              void* d_out, int out_size, void* d_ws, size_t ws_size,
                              hipStream_t stream) {
  (void)n_in; (void)out_size; (void)ws_size;  // needs ~313 KB of ws
  const float* x    = (const float*)d_in[0];
  const float* W0   = (const float*)d_in[1];
  const float* b0   = (const float*)d_in[2];
  const float* Wh   = (const float*)d_in[3];
  const float* bh   = (const float*)d_in[4];
  const float* Wout = (const float*)d_in[5];
  const float* bout = (const float*)d_in[6];
  float* out = (float*)d_out;

  char* ws = (char*)d_ws;
  _Float16* wfrag   = (_Float16*)(ws);
  _Float16* w0frag  = (_Float16*)(ws + 294912);
  float*    biasC   = (float*)(ws + 299008);
  _Float16* woutf16 = (_Float16*)(ws + 304128);

  const int n = in_sizes[0] / 4;  // 1048576 points

  prep_kernel<<<dim3(160), dim3(256), 0, stream>>>(W0, b0, Wh, bh, Wout,
                                                   wfrag, w0frag, biasC, woutf16);
  mlp_fused<<<dim3(n / 256), dim3(256), 0, stream>>>(x, wfrag, w0frag, biasC,
                                                     woutf16, bout, out);
}

// Round 13
// 260.909 us; speedup vs baseline: 1.0556x; 1.0556x over previous
//
#include <hip/hip_runtime.h>
#include <stdint.h>

// ---------------- types ----------------
typedef _Float16 f16x8 __attribute__((ext_vector_type(8)));
typedef __fp16   fp16x2 __attribute__((ext_vector_type(2)));
typedef float    f32x16 __attribute__((ext_vector_type(16)));

union Frag {
  f16x8    v;
  uint32_t w[4];
  _Float16 h[8];
};

union CVec {
  float4 q[4];
  f32x16 v;
};

__device__ __forceinline__ uint32_t pack2h(float a, float b) {
  union { _Float16 h[2]; uint32_t u; } r;
  r.h[0] = (_Float16)a;   // RNE f32->f16
  r.h[1] = (_Float16)b;
  return r.u;
}

__device__ __forceinline__ uint32_t pkrtz(float a, float b) {
  union { fp16x2 h2; uint32_t u; } cv;
  cv.h2 = __builtin_amdgcn_cvt_pkrtz(a, b);
  return cv.u;
}

__device__ __forceinline__ void g2lds16(const void* g, void* l) {
  __builtin_amdgcn_global_load_lds(
      (const __attribute__((address_space(1))) uint32_t*)g,
      (__attribute__((address_space(3))) uint32_t*)l, 16, 0, 0);
}

// Channel relabeling (involution) applied to W rows + bias of EVERY layer:
// slot s (0..31 within a 32-tile) holds logical channel lam32(s).
// With this, D-reg pairs are already in B-fragment k-order -> NO lane exchange.
__host__ __device__ __forceinline__ int lam32(int s) {
  return (((s >> 2) ^ (s >> 3)) & 1) ? (s ^ 12) : s;
}

// ---------------- prep: fragment-order the weights (f16) ----------------
// ws layout (bytes):
//   wfrag   @ 0      : [9][8 kt][4 ot][64 lane][8 j] f16  = 294912 B  (streaming order)
//   w0frag  @ 294912 : [4 ot][64 lane][8 j]          f16  = 4096 B   (K padded 4->16)
//   biasC   @ 299008 : [10 l][4 ot][2 h][16 r]       f32  = 5120 B   (MFMA C-operand order)
//   woutf16 @ 304128 : [8 kt][64 lane][8 j]          f16  = 8192 B   (A-frag, rows!=0 zeroed)
// fragment value convention (32x32x16 f16 MFMA):
//   A lane l holds row i = l&31, k = (l>>5)*8 + j
//   B lane l holds col j = l&31, k = (l>>5)*8 + j
//   D/C lane l holds col = l&31, row r: slot = (r&3) + 8*(r>>2) + 4*(l>>5)
// Hybrid W delivery: kt0-5 (24KB/layer) staged to LDS; kt6-7 (8KB/layer) read
// straight from global through L1 (same addresses for all waves -> L1 broadcast).
__global__ void prep_kernel(const float* __restrict__ W0, const float* __restrict__ b0,
                            const float* __restrict__ Wh, const float* __restrict__ bh,
                            const float* __restrict__ Wout,
                            _Float16* __restrict__ wfrag, _Float16* __restrict__ w0frag,
                            float* __restrict__ biasC, _Float16* __restrict__ woutf16) {
  const int stride = gridDim.x * blockDim.x;
  for (int idx = blockIdx.x * blockDim.x + threadIdx.x; idx < 154880; idx += stride) {
    if (idx < 147456) {                       // wfrag: Wh[l][lam(o)][k], [l][kt][ot] order
      const int j = idx & 7, lane = (idx >> 3) & 63, ot = (idx >> 9) & 3,
                kt = (idx >> 11) & 7, l = idx >> 14;
      const int o = ot * 32 + lam32(lane & 31);
      const int k = kt * 16 + (lane >> 5) * 8 + j;
      wfrag[idx] = (_Float16)Wh[(l * 128 + o) * 128 + k];
    } else if (idx < 147456 + 2048) {         // w0frag (K padded with zeros), rows lam'd
      const int i = idx - 147456;
      const int j = i & 7, lane = (i >> 3) & 63, ot = i >> 9;
      const int o = ot * 32 + lam32(lane & 31);
      const int k = (lane >> 5) * 8 + j;
      w0frag[i] = (_Float16)(k < 4 ? W0[o * 4 + k] : 0.0f);
    } else if (idx < 147456 + 2048 + 1280) {  // biasC: C-operand order per (l,ot,h), lam'd
      const int i = idx - (147456 + 2048);
      const int r = i & 15, hh = (i >> 4) & 1, ot = (i >> 5) & 3, l = i >> 7;
      const int slot = (r & 3) + 8 * (r >> 2) + 4 * hh;
      const int o = ot * 32 + lam32(slot);
      biasC[i] = (l == 0) ? b0[o] : bh[(l - 1) * 128 + o];
    } else {                                  // Wout as masked A-fragment (row 0 only), f16
      const int i = idx - (147456 + 2048 + 1280);
      const int j = i & 7, lane = (i >> 3) & 63, kt = i >> 9;
      const int k = kt * 16 + (lane >> 5) * 8 + j;   // logical k — unchanged
      woutf16[i] = ((lane & 31) == 0) ? (_Float16)Wout[k] : (_Float16)0.0f;
    }
  }
}

// ---------------- fused MLP: 256 threads, 4 waves x 64 rows (nt=2) ----------------
// Hybrid W (LDS kt0-5 + global kt6-7) splits delivery across both memory pipes.
// Odd-parity blocks sleep ~4000cyc once so the 2 blocks/CU run half-period out of
// phase: one block's MFMA phase covers the other's epilogue/staging phase.
__global__ __launch_bounds__(256, 2) void mlp_fused(
    const float* __restrict__ x,
    const _Float16* __restrict__ wfrag,
    const _Float16* __restrict__ w0frag,
    const float* __restrict__ biasCg,
    const _Float16* __restrict__ woutf16,
    const float* __restrict__ boutp,
    float* __restrict__ out) {
  // 2 x 24 KB W double-buffer (kt0-5) + bias C-table; 54.3 KB -> 2 blocks/CU
  __shared__ __align__(16) unsigned char ldsW[2][24576];
  __shared__ __align__(16) float ldsBiasC[1280];

  const int t    = threadIdx.x;
  const int lane = t & 63;
  const int wv   = t >> 6;
  const int h    = lane >> 5;   // half-wave
  const int ln   = lane & 31;
  const long rowbase = (long)blockIdx.x * 256 + wv * 64;  // + nt*32 + ln

  // ---- prologue staging: W[1] kt0-5 -> ldsW[0]; bias C-table ----
  {
    const unsigned char* src = (const unsigned char*)wfrag;  // layer 1 at offset 0
#pragma unroll
    for (int i = 0; i < 6; ++i) {
      const int off = i * 4096 + t * 16;
      g2lds16(src + off, &ldsW[0][off]);
    }
    const unsigned char* bsrc = (const unsigned char*)biasCg;
    g2lds16(bsrc + t * 16, (unsigned char*)ldsBiasC + t * 16);            // chunks 0..255
    if (t < 64) g2lds16(bsrc + (256 + t) * 16, (unsigned char*)ldsBiasC + (256 + t) * 16);
  }

  Frag   B[2][8];      // current-layer input fragments (H^T), per nt / k-tile
  f32x16 acc[4][2];    // [o-tile][n-tile], D = H_out^T
  const f32x16 fzero = (f32x16)0.0f;

  // broadcast read of the per-(layer,ot,half) C-operand (bias pre-placed in D order)
  auto load_cvec = [&](int l, int ot) -> f32x16 {
    CVec cv;
    const float* p = ldsBiasC + ((l * 4 + ot) * 2 + h) * 16;
#pragma unroll
    for (int g = 0; g < 4; ++g) cv.q[g] = *(const float4*)(p + g * 4);
    return cv.v;
  };

  // x loads + pack overlap the staging latency
  Frag xb[2];
#pragma unroll
  for (int nt = 0; nt < 2; ++nt) {
    float4 xv = make_float4(0.f, 0.f, 0.f, 0.f);
    if (h == 0) xv = *(const float4*)(x + (rowbase + nt * 32 + ln) * 4);
    xb[nt].w[0] = pack2h(xv.x, xv.y);
    xb[nt].w[1] = pack2h(xv.z, xv.w);
    xb[nt].w[2] = 0u;
    xb[nt].w[3] = 0u;
  }

  __syncthreads();  // staging drained (implicit vmcnt(0) lgkmcnt(0) before barrier)

  // ---- half-period phase offset: odd-parity blocks sleep ~4000 cyc once so the
  // two co-resident blocks anti-phase (parity robust to +1/+8/+2048 pairings) ----
  if ((blockIdx.x ^ (blockIdx.x >> 3) ^ (blockIdx.x >> 11)) & 1)
    asm volatile("s_sleep 62");

  // ---- layer 0: K=16 zero-padded MFMA, C = bias ----
#pragma unroll
  for (int ot = 0; ot < 4; ++ot) {
    const f16x8 a0 = *(const f16x8*)(w0frag + ot * 512 + lane * 8);
    const f32x16 cvec = load_cvec(0, ot);
    acc[ot][0] = __builtin_amdgcn_mfma_f32_32x32x16_f16(a0, xb[0].v, cvec, 0, 0, 0);
    acc[ot][1] = __builtin_amdgcn_mfma_f32_32x32x16_f16(a0, xb[1].v, cvec, 0, 0, 0);
  }

  // epilogue: relu+pack straight from acc pairs (lam32 pre-permutation makes the
  // D-reg order equal the B-fragment k-order — no lane exchange, no moves).
  auto do_epilogue = [&]() {
#pragma unroll
    for (int ot = 0; ot < 4; ++ot) {
#pragma unroll
      for (int nt = 0; nt < 2; ++nt) {
#pragma unroll
        for (int u = 0; u < 2; ++u) {      // B k-tile half: acc regs 8u..8u+7
          Frag nb;
#pragma unroll
          for (int j = 0; j < 4; ++j) {
            const uint32_t cv = pkrtz(acc[ot][nt][8 * u + 2 * j],
                                      acc[ot][nt][8 * u + 2 * j + 1]);
            uint32_t r;
            asm("v_pk_max_f16 %0, %1, %2" : "=v"(r) : "v"(cv), "v"(0u));
            nb.w[j] = r;
          }
          B[nt][ot * 2 + u] = nb;
        }
      }
    }
  };

  // ---- rotated pipeline: R(l) = {prefetch W[l+1] kt0-5; epilogue(l-1); MFMA(l)} ----
  // Rotating A-fragment refill: kt+1 < 6 from LDS, kt+1 in {6,7} from global/L1.
#pragma unroll
  for (int l = 1; l <= 9; ++l) {
    if (l < 9) {  // prefetch W[l+1] kt0-5 into buf[l&1]
      const unsigned char* src = (const unsigned char*)wfrag + (size_t)l * 32768;
#pragma unroll
      for (int i = 0; i < 6; ++i) {
        const int off = i * 4096 + t * 16;
        g2lds16(src + off, &ldsW[l & 1][off]);
      }
    }
    const unsigned char* wl = &ldsW[(l - 1) & 1][0];
    const _Float16* wg = wfrag + (size_t)(l - 1) * 16384;   // global view of this layer

    f16x8 a[4];
#pragma unroll
    for (int ot = 0; ot < 4; ++ot)   // preload kt=0 fragments (latency under epilogue)
      a[ot] = *(const f16x8*)(wl + ot * 1024 + lane * 16);

    do_epilogue();  // acc(l-1) -> B (register-only; overlaps load latency)

    __builtin_amdgcn_s_setprio(1);
#pragma unroll
    for (int kt = 0; kt < 8; ++kt) {
#pragma unroll
      for (int ot = 0; ot < 4; ++ot) {
        if (kt == 0) {
          const f32x16 cvec = load_cvec(l, ot);
          acc[ot][0] = __builtin_amdgcn_mfma_f32_32x32x16_f16(a[ot], B[0][kt].v, cvec, 0, 0, 0);
          acc[ot][1] = __builtin_amdgcn_mfma_f32_32x32x16_f16(a[ot], B[1][kt].v, cvec, 0, 0, 0);
        } else {
          acc[ot][0] = __builtin_amdgcn_mfma_f32_32x32x16_f16(a[ot], B[0][kt].v, acc[ot][0], 0, 0, 0);
          acc[ot][1] = __builtin_amdgcn_mfma_f32_32x32x16_f16(a[ot], B[1][kt].v, acc[ot][1], 0, 0, 0);
        }
        if (kt < 7) {  // refill the just-freed fragment register with kt+1's data
          if (kt + 1 < 6)
            a[ot] = *(const f16x8*)(wl + ((kt + 1) * 4 + ot) * 1024 + lane * 16);
          else
            a[ot] = *(const f16x8*)(wg + ((kt + 1) * 4 + ot) * 512 + lane * 8);
        }
      }
    }
    __builtin_amdgcn_s_setprio(0);
    if (l < 9) __syncthreads();  // gates buf reuse; drains prefetch W[l+1]
  }

  // ---- output layer: MFMA with masked Wout A-fragment (row 0 only) ----
  // D row 0 lives in reg 0 of lanes 0..31 -> no shuffle reduce needed.
  {
    Frag wa[8];
#pragma unroll
    for (int kt = 0; kt < 8; ++kt)
      wa[kt].v = *(const f16x8*)(woutf16 + kt * 512 + lane * 8);
    const float boutv = *boutp;

    do_epilogue();  // layer 9 acc -> B

    f32x16 accO0 = fzero, accO1 = fzero;
#pragma unroll
    for (int kt = 0; kt < 8; ++kt) {
      accO0 = __builtin_amdgcn_mfma_f32_32x32x16_f16(wa[kt].v, B[0][kt].v, accO0, 0, 0, 0);
      accO1 = __builtin_amdgcn_mfma_f32_32x32x16_f16(wa[kt].v, B[1][kt].v, accO1, 0, 0, 0);
    }
    if (h == 0) {
      out[rowbase + ln]      = accO0[0] + boutv;
      out[rowbase + 32 + ln] = accO1[0] + boutv;
    }
  }
}

extern "C" void kernel_launch(void* const* d_in, const int* in_sizes, int n_in,
                              void* d_out, int out_size, void* d_ws, size_t ws_size,
                              hipStream_t stream) {
  (void)n_in; (void)out_size; (void)ws_size;  // needs ~313 KB of ws
  const float* x    = (const float*)d_in[0];
  const float* W0   = (const float*)d_in[1];
  const float* b0   = (const float*)d_in[2];
  const float* Wh   = (const float*)d_in[3];
  const float* bh   = (const float*)d_in[4];
  const float* Wout = (const float*)d_in[5];
  const float* bout = (const float*)d_in[6];
  float* out = (float*)d_out;

  char* ws = (char*)d_ws;
  _Float16* wfrag   = (_Float16*)(ws);
  _Float16* w0frag  = (_Float16*)(ws + 294912);
  float*    biasC   = (float*)(ws + 299008);
  _Float16* woutf16 = (_Float16*)(ws + 304128);

  const int n = in_sizes[0] / 4;  // 1048576 points

  prep_kernel<<<dim3(160), dim3(256), 0, stream>>>(W0, b0, Wh, bh, Wout,
                                                   wfrag, w0frag, biasC, woutf16);
  mlp_fused<<<dim3(n / 256), dim3(256), 0, stream>>>(x, wfrag, w0frag, biasC,
                                                     woutf16, bout, out);
}

// Round 14
// 253.311 us; speedup vs baseline: 1.0873x; 1.0300x over previous
//
#include <hip/hip_runtime.h>
#include <stdint.h>

// ---------------- types ----------------
typedef _Float16 f16x8 __attribute__((ext_vector_type(8)));
typedef __fp16   fp16x2 __attribute__((ext_vector_type(2)));
typedef float    f32x16 __attribute__((ext_vector_type(16)));

union Frag {
  f16x8    v;
  uint32_t w[4];
  _Float16 h[8];
};

union CVec {
  float4 q[4];
  f32x16 v;
};

__device__ __forceinline__ uint32_t pack2h(float a, float b) {
  union { _Float16 h[2]; uint32_t u; } r;
  r.h[0] = (_Float16)a;   // RNE f32->f16
  r.h[1] = (_Float16)b;
  return r.u;
}

__device__ __forceinline__ uint32_t pkrtz(float a, float b) {
  union { fp16x2 h2; uint32_t u; } cv;
  cv.h2 = __builtin_amdgcn_cvt_pkrtz(a, b);
  return cv.u;
}

__device__ __forceinline__ void g2lds16(const void* g, void* l) {
  __builtin_amdgcn_global_load_lds(
      (const __attribute__((address_space(1))) uint32_t*)g,
      (__attribute__((address_space(3))) uint32_t*)l, 16, 0, 0);
}

// Channel relabeling (involution) applied to W rows + bias of EVERY layer:
// slot s (0..31 within a 32-tile) holds logical channel lam32(s).
// With this, D-reg pairs are already in B-fragment k-order -> NO lane exchange.
__host__ __device__ __forceinline__ int lam32(int s) {
  return (((s >> 2) ^ (s >> 3)) & 1) ? (s ^ 12) : s;
}

// ---------------- prep: fragment-order the weights (f16) ----------------
// ws layout (bytes):
//   wfrag   @ 0      : [9][4 ot][8 kt][64 lane][8 j] f16  = 294912 B
//   w0frag  @ 294912 : [4 ot][64 lane][8 j]          f16  = 4096 B   (K padded 4->16)
//   biasC   @ 299008 : [10 l][4 ot][2 h][16 r]       f32  = 5120 B   (MFMA C-operand order)
//   woutf16 @ 304128 : [8 kt][64 lane][8 j]          f16  = 8192 B   (A-frag, rows!=0 zeroed)
// fragment value convention (32x32x16 f16 MFMA):
//   A lane l holds row i = l&31, k = (l>>5)*8 + j
//   B lane l holds col j = l&31, k = (l>>5)*8 + j
//   D/C lane l holds col = l&31, row r: slot = (r&3) + 8*(r>>2) + 4*(l>>5)
// Rows of W/bias are stored at slot s holding logical channel lam32(s), so that
// adjacent acc pairs pack directly into next-layer B fragments (no lane swap).
__global__ void prep_kernel(const float* __restrict__ W0, const float* __restrict__ b0,
                            const float* __restrict__ Wh, const float* __restrict__ bh,
                            const float* __restrict__ Wout,
                            _Float16* __restrict__ wfrag, _Float16* __restrict__ w0frag,
                            float* __restrict__ biasC, _Float16* __restrict__ woutf16) {
  const int stride = gridDim.x * blockDim.x;
  for (int idx = blockIdx.x * blockDim.x + threadIdx.x; idx < 154880; idx += stride) {
    if (idx < 147456) {                       // wfrag: Wh[l][lam(o)][k] -> A-fragment order
      const int j = idx & 7, lane = (idx >> 3) & 63, kt = (idx >> 9) & 7,
                ot = (idx >> 12) & 3, l = idx >> 14;
      const int o = ot * 32 + lam32(lane & 31);
      const int k = kt * 16 + (lane >> 5) * 8 + j;
      wfrag[idx] = (_Float16)Wh[(l * 128 + o) * 128 + k];
    } else if (idx < 147456 + 2048) {         // w0frag (K padded with zeros), rows lam'd
      const int i = idx - 147456;
      const int j = i & 7, lane = (i >> 3) & 63, ot = i >> 9;
      const int o = ot * 32 + lam32(lane & 31);
      const int k = (lane >> 5) * 8 + j;
      w0frag[i] = (_Float16)(k < 4 ? W0[o * 4 + k] : 0.0f);
    } else if (idx < 147456 + 2048 + 1280) {  // biasC: C-operand order per (l,ot,h), lam'd
      const int i = idx - (147456 + 2048);
      const int r = i & 15, hh = (i >> 4) & 1, ot = (i >> 5) & 3, l = i >> 7;
      const int slot = (r & 3) + 8 * (r >> 2) + 4 * hh;
      const int o = ot * 32 + lam32(slot);
      biasC[i] = (l == 0) ? b0[o] : bh[(l - 1) * 128 + o];
    } else {                                  // Wout as masked A-fragment (row 0 only), f16
      const int i = idx - (147456 + 2048 + 1280);
      const int j = i & 7, lane = (i >> 3) & 63, kt = i >> 9;
      const int k = kt * 16 + (lane >> 5) * 8 + j;   // logical k — unchanged
      woutf16[i] = ((lane & 31) == 0) ? (_Float16)Wout[k] : (_Float16)0.0f;
    }
  }
}

// ---------------- fused MLP: 256 threads, 4 waves x 64 rows (nt=2) ----------------
// Best-measured base (R10: 250.5us, MfmaUtil 62%) + ONE change: deterministic
// half-period phase offset between the 2 co-resident blocks per CU, keyed to the
// HW wave-slot (WAVE_ID parity of wave 0, broadcast block-wide via LDS).
__global__ __launch_bounds__(256, 2) void mlp_fused(
    const float* __restrict__ x,
    const _Float16* __restrict__ wfrag,
    const _Float16* __restrict__ w0frag,
    const float* __restrict__ biasCg,
    const _Float16* __restrict__ woutf16,
    const float* __restrict__ boutp,
    float* __restrict__ out) {
  // 2 x 32 KB W double-buffer + bias C-table; 70.7 KB -> 2 blocks/CU
  __shared__ __align__(16) unsigned char ldsW[2][32768];
  __shared__ __align__(16) float ldsBiasC[1280];
  __shared__ int ldsPhase;

  const int t    = threadIdx.x;
  const int lane = t & 63;
  const int wv   = t >> 6;
  const int h    = lane >> 5;   // half-wave
  const int ln   = lane & 31;
  const long rowbase = (long)blockIdx.x * 256 + wv * 64;  // + nt*32 + ln

  // block-uniform phase flag from wave 0's HW wave slot (co-resident blocks land
  // in different slots on each SIMD -> flag differs between the two blocks)
  if (t == 0) {
    uint32_t hwid;
    asm volatile("s_getreg_b32 %0, hwreg(HW_REG_HW_ID)" : "=s"(hwid));
    ldsPhase = (int)(hwid & 1u);   // WAVE_ID[0]
  }

  // ---- prologue staging: W[1] -> ldsW[0]; bias C-table ----
  {
    const unsigned char* src = (const unsigned char*)wfrag;  // layer 1 at offset 0
#pragma unroll
    for (int i = 0; i < 8; ++i) {
      const int off = i * 4096 + t * 16;
      g2lds16(src + off, &ldsW[0][off]);
    }
    const unsigned char* bsrc = (const unsigned char*)biasCg;
    g2lds16(bsrc + t * 16, (unsigned char*)ldsBiasC + t * 16);            // chunks 0..255
    if (t < 64) g2lds16(bsrc + (256 + t) * 16, (unsigned char*)ldsBiasC + (256 + t) * 16);
  }

  Frag   B[2][8];      // current-layer input fragments (H^T), per nt / k-tile
  f32x16 acc[4][2];    // [o-tile][n-tile], D = H_out^T
  const f32x16 fzero = (f32x16)0.0f;

  // broadcast read of the per-(layer,ot,half) C-operand (bias pre-placed in D order)
  auto load_cvec = [&](int l, int ot) -> f32x16 {
    CVec cv;
    const float* p = ldsBiasC + ((l * 4 + ot) * 2 + h) * 16;
#pragma unroll
    for (int g = 0; g < 4; ++g) cv.q[g] = *(const float4*)(p + g * 4);
    return cv.v;
  };

  // x loads + pack overlap the staging latency
  Frag xb[2];
#pragma unroll
  for (int nt = 0; nt < 2; ++nt) {
    float4 xv = make_float4(0.f, 0.f, 0.f, 0.f);
    if (h == 0) xv = *(const float4*)(x + (rowbase + nt * 32 + ln) * 4);
    xb[nt].w[0] = pack2h(xv.x, xv.y);
    xb[nt].w[1] = pack2h(xv.z, xv.w);
    xb[nt].w[2] = 0u;
    xb[nt].w[3] = 0u;
  }

  __syncthreads();  // staging + phase flag ready

  // ---- half-period offset: one of the two co-resident blocks sleeps ~4000 cyc
  // once, so its MFMA phases overlay the other block's epilogue/staging phases ----
  if (ldsPhase) asm volatile("s_sleep 62");

  // ---- layer 0: K=16 zero-padded MFMA, C = bias ----
#pragma unroll
  for (int ot = 0; ot < 4; ++ot) {
    const f16x8 a0 = *(const f16x8*)(w0frag + ot * 512 + lane * 8);
    const f32x16 cvec = load_cvec(0, ot);
    acc[ot][0] = __builtin_amdgcn_mfma_f32_32x32x16_f16(a0, xb[0].v, cvec, 0, 0, 0);
    acc[ot][1] = __builtin_amdgcn_mfma_f32_32x32x16_f16(a0, xb[1].v, cvec, 0, 0, 0);
  }

  // epilogue: relu+pack straight from acc pairs (lam32 pre-permutation makes the
  // D-reg order equal the B-fragment k-order — no lane exchange, no moves).
  auto do_epilogue = [&]() {
#pragma unroll
    for (int ot = 0; ot < 4; ++ot) {
#pragma unroll
      for (int nt = 0; nt < 2; ++nt) {
#pragma unroll
        for (int u = 0; u < 2; ++u) {      // B k-tile half: acc regs 8u..8u+7
          Frag nb;
#pragma unroll
          for (int j = 0; j < 4; ++j) {
            const uint32_t cv = pkrtz(acc[ot][nt][8 * u + 2 * j],
                                      acc[ot][nt][8 * u + 2 * j + 1]);
            uint32_t r;
            asm("v_pk_max_f16 %0, %1, %2" : "=v"(r) : "v"(cv), "v"(0u));
            nb.w[j] = r;
          }
          B[nt][ot * 2 + u] = nb;
        }
      }
    }
  };

  // ---- rotated pipeline: R(l) = {prefetch W[l+1]; epilogue(l-1); MFMA(l); barrier} ----
  // Rotating A-fragment refill + pinned {2 MFMA, 1 ds_read} interleave.
#pragma unroll
  for (int l = 1; l <= 9; ++l) {
    if (l < 9) {  // prefetch W[l+1] into buf[l&1] (last read by layer l-1, pre-barrier)
      const unsigned char* src = (const unsigned char*)wfrag + (size_t)l * 32768;
#pragma unroll
      for (int i = 0; i < 8; ++i) {
        const int off = i * 4096 + t * 16;
        g2lds16(src + off, &ldsW[l & 1][off]);
      }
    }
    do_epilogue();  // acc(l-1) -> B (register-only; overlaps load issue)
    const unsigned char* wl = &ldsW[(l - 1) & 1][0];

    f16x8 a[4];
#pragma unroll
    for (int ot = 0; ot < 4; ++ot)   // preload kt=0 fragments
      a[ot] = *(const f16x8*)(wl + ot * 8192 + lane * 16);

#pragma unroll
    for (int kt = 0; kt < 8; ++kt) {
#pragma unroll
      for (int ot = 0; ot < 4; ++ot) {
        if (kt == 0) {
          const f32x16 cvec = load_cvec(l, ot);
          acc[ot][0] = __builtin_amdgcn_mfma_f32_32x32x16_f16(a[ot], B[0][kt].v, cvec, 0, 0, 0);
          acc[ot][1] = __builtin_amdgcn_mfma_f32_32x32x16_f16(a[ot], B[1][kt].v, cvec, 0, 0, 0);
        } else {
          acc[ot][0] = __builtin_amdgcn_mfma_f32_32x32x16_f16(a[ot], B[0][kt].v, acc[ot][0], 0, 0, 0);
          acc[ot][1] = __builtin_amdgcn_mfma_f32_32x32x16_f16(a[ot], B[1][kt].v, acc[ot][1], 0, 0, 0);
        }
        if (kt < 7)   // refill the just-freed fragment register with kt+1's data
          a[ot] = *(const f16x8*)(wl + ot * 8192 + (kt + 1) * 1024 + lane * 16);
        __builtin_amdgcn_sched_group_barrier(0x008, 2, 0);  // MFMA
        if (kt < 7)
          __builtin_amdgcn_sched_group_barrier(0x100, 1, 0);  // DS_READ
      }
    }
    if (l < 9) __syncthreads();  // gates buf reuse; drains prefetch W[l+1]
  }

  // ---- output layer: MFMA with masked Wout A-fragment (row 0 only) ----
  // D row 0 lives in reg 0 of lanes 0..31 -> no shuffle reduce needed.
  {
    Frag wa[8];
#pragma unroll
    for (int kt = 0; kt < 8; ++kt)
      wa[kt].v = *(const f16x8*)(woutf16 + kt * 512 + lane * 8);
    const float boutv = *boutp;

    do_epilogue();  // layer 9 acc -> B

    f32x16 accO0 = fzero, accO1 = fzero;
#pragma unroll
    for (int kt = 0; kt < 8; ++kt) {
      accO0 = __builtin_amdgcn_mfma_f32_32x32x16_f16(wa[kt].v, B[0][kt].v, accO0, 0, 0, 0);
      accO1 = __builtin_amdgcn_mfma_f32_32x32x16_f16(wa[kt].v, B[1][kt].v, accO1, 0, 0, 0);
    }
    if (h == 0) {
      out[rowbase + ln]      = accO0[0] + boutv;
      out[rowbase + 32 + ln] = accO1[0] + boutv;
    }
  }
}

extern "C" void kernel_launch(void* const* d_in, const int* in_sizes, int n_in,
                              void* d_out, int out_size, void* d_ws, size_t ws_size,
                              hipStream_t stream) {
  (void)n_in; (void)out_size; (void)ws_size;  // needs ~313 KB of ws
  const float* x    = (const float*)d_in[0];
  const float* W0   = (const float*)d_in[1];
  const float* b0   = (const float*)d_in[2];
  const float* Wh   = (const float*)d_in[3];
  const float* bh   = (const float*)d_in[4];
  const float* Wout = (const float*)d_in[5];
  const float* bout = (const float*)d_in[6];
  float* out = (float*)d_out;

  char* ws = (char*)d_ws;
  _Float16* wfrag   = (_Float16*)(ws);
  _Float16* w0frag  = (_Float16*)(ws + 294912);
  float*    biasC   = (float*)(ws + 299008);
  _Float16* woutf16 = (_Float16*)(ws + 304128);

  const int n = in_sizes[0] / 4;  // 1048576 points

  prep_kernel<<<dim3(160), dim3(256), 0, stream>>>(W0, b0, Wh, bh, Wout,
                                                   wfrag, w0frag, biasC, woutf16);
  mlp_fused<<<dim3(n / 256), dim3(256), 0, stream>>>(x, wfrag, w0frag, biasC,
                                                     woutf16, bout, out);
}